// Round 14
// baseline (871.764 us; speedup 1.0000x reference)
//
#include <hip/hip_runtime.h>
#include <stdint.h>

#define BB 256
#define TT 128
#define DD 512
#define HH 512
#define G4 2048      // 4H

typedef short bf16x8 __attribute__((ext_vector_type(8)));
typedef float f32x4  __attribute__((ext_vector_type(4)));
typedef int   i32x4  __attribute__((ext_vector_type(4)));

__device__ __forceinline__ unsigned short f2bf(float f){
  union { float f; unsigned u; } v; v.f = f;
  unsigned u = v.u;
  unsigned r = (u + 0x7FFFu + ((u >> 16) & 1u)) >> 16;
  return (unsigned short)r;
}
__device__ __forceinline__ float bf2f(unsigned short s){
  union { unsigned u; float f; } v; v.u = ((unsigned)s) << 16;
  return v.f;
}
__device__ __forceinline__ float sigf(float x){
  return __builtin_amdgcn_rcpf(1.0f + __expf(-x));
}
__device__ __forceinline__ float tanhfast(float x){
  return 1.0f - 2.0f*__builtin_amdgcn_rcpf(1.0f + __expf(2.0f*x));
}

// x [B,T,D] f32 -> xtr [T,B,D] bf16
__global__ void prep_x_k(const float* __restrict__ x, unsigned short* __restrict__ xtr){
  const int n4 = BB*TT*(DD/4);
  for (int i = blockIdx.x*blockDim.x + threadIdx.x; i < n4; i += gridDim.x*blockDim.x){
    int d4 = i & (DD/4 - 1);
    int b  = (i / (DD/4)) & (BB-1);
    int t  = i / ((DD/4)*BB);
    float4 v = *(const float4*)(x + (((size_t)b*TT + t)*DD + (size_t)d4*4));
    ushort4 o;
    o.x = f2bf(v.x); o.y = f2bf(v.y); o.z = f2bf(v.z); o.w = f2bf(v.w);
    *(ushort4*)(xtr + (((size_t)t*BB + b)*DD + (size_t)d4*4)) = o;
  }
}

// wupk[arr][d][hb(32)][ks(16)][gf(4)][lane(64)][e(8)] bf16
__global__ void prep_wu_k(const float* __restrict__ Wf, const float* __restrict__ Uf,
                          const float* __restrict__ Wb, const float* __restrict__ Ub,
                          unsigned short* __restrict__ wupk){
  const int tot = 2*2*32*16*4*64*8;  // 4,194,304
  for (int i = blockIdx.x*blockDim.x + threadIdx.x; i < tot; i += gridDim.x*blockDim.x){
    int e    = i & 7;
    int lane = (i >> 3) & 63;
    int gf   = (i >> 9) & 3;
    int ks   = (i >> 11) & 15;
    int hb   = (i >> 15) & 31;
    int d    = (i >> 20) & 1;
    int arr  = (i >> 21) & 1;
    int jl = lane & 15, q = lane >> 4;
    int n = gf*HH + hb*16 + jl;
    int k = ks*32 + q*8 + e;
    const float* src = arr ? (d ? Ub : Uf) : (d ? Wb : Wf);
    wupk[i] = f2bf(src[(size_t)k*G4 + n]);
  }
}

// bias_pk[d][hb(32)][gf(4)][jl(16)]
__global__ void prep_bias_k(const float* __restrict__ bf_, const float* __restrict__ bb_,
                            float* __restrict__ bias_pk){
  int i = blockIdx.x*blockDim.x + threadIdx.x;
  if (i < 2*32*4*16){
    int jl = i & 15;
    int gf = (i >> 4) & 3;
    int hb = (i >> 6) & 31;
    int d  = i >> 11;
    const float* src = d ? bb_ : bf_;
    bias_pk[i] = src[gf*HH + hb*16 + jl];
  }
}

// Persistent LSTM: R13 structure with per-wave flags (no LDS go/done hops),
// ringB XOR-swizzle (bank-conflict-free), s_sleep producer backoff.
// 256 blocks x 384 thr (6 waves), 1 block/CU (LDS-forced), regular launch.
// Registration (R10): g = physical XCD, hb = rank; surplus fills deficits.
// Waves 0-3: chain over group-rows w*16..+16; each wave publishes its OWN
//   flag [g][hb*4+w] after draining h stores; each wave polls all 128 flags
//   (2 words/lane). h data: pure -> plain stores + sc0 loads (XCD L2);
//   impure -> agent (R8).
// Waves 4-5: x.W+b producers -> 2-slot LDS bf16 ring (<=2 steps ahead).
__global__ __launch_bounds__(384, 1)
void lstm_fused_k(const unsigned short* __restrict__ xtr,
                  const unsigned short* __restrict__ wupk,
                  const float* __restrict__ bias_pk,
                  unsigned short* hgrp,
                  int* flags, int* xcdcnt,
                  float* __restrict__ out)
{
  __shared__ __align__(1024) unsigned short Wl[32768];     // 64KB [ks16][gf4][lane][8]
  __shared__ __align__(1024) unsigned short Ul[32768];     // 64KB
  __shared__ __align__(1024) unsigned short ringB[2][4096];// 16KB [slot][row64][col64^swz]
  __shared__ int xseq[2];
  __shared__ int cseq[4];
  __shared__ int shId[4];

  const int tid  = threadIdx.x;
  const int lane = tid & 63;
  const int w    = tid >> 6;          // 0..5
  const int jl   = lane & 15, q = lane >> 4;

  // ---- registration (R10-proven): hang-free XCD identity ----
  if (tid == 0){
    unsigned xcd;
    asm volatile("s_getreg_b32 %0, hwreg(HW_REG_XCC_ID)" : "=s"(xcd));
    int x = (int)(xcd & 7);
    int rank = __hip_atomic_fetch_add(&xcdcnt[x], 1, __ATOMIC_RELAXED, __HIP_MEMORY_SCOPE_AGENT);
    __hip_atomic_fetch_add(&xcdcnt[8], 1, __ATOMIC_RELEASE, __HIP_MEMORY_SCOPE_AGENT);
    while (__hip_atomic_load(&xcdcnt[8], __ATOMIC_ACQUIRE, __HIP_MEMORY_SCOPE_AGENT) < 256)
      __builtin_amdgcn_s_sleep(2);
    int n[8];
    #pragma unroll
    for (int i = 0; i < 8; ++i)
      n[i] = __hip_atomic_load(&xcdcnt[i], __ATOMIC_RELAXED, __HIP_MEMORY_SCOPE_AGENT);
    int gg = 0, hh = 0;
    if (rank < 32){ gg = x; hh = rank; }
    else {
      int k = rank - 32;
      for (int i = 0; i < x; ++i) if (n[i] > 32) k += n[i] - 32;
      for (int i = 0; i < 8; ++i){
        int def = 32 - n[i];
        if (def > 0){
          if (k < def){ gg = i; hh = n[i] + k; break; }
          k -= def;
        }
      }
    }
    shId[0] = gg; shId[1] = hh; shId[2] = (n[gg] >= 32) ? 1 : 0;
  }
  if (tid < 2) xseq[tid] = 0;
  if (tid < 4) cseq[tid] = 0;
  __syncthreads();
  const int g    = shId[0];
  const int hb   = shId[1];
  const int pure = shId[2];
  const int d    = g >> 2;
  const int mq   = g & 3;
  const int m0   = mq * 64;

  // ---- stage W and U slices (linear fragment order) ----
  const unsigned short* wsrc = wupk + ((size_t)(0*2 + d)*32 + hb)*32768;
  const unsigned short* usrc = wupk + ((size_t)(1*2 + d)*32 + hb)*32768;
  for (int u = tid; u < 4096; u += 384){
    __builtin_amdgcn_global_load_lds(
      (const __attribute__((address_space(1))) void*)(wsrc + (size_t)u*8),
      (__attribute__((address_space(3))) void*)(Wl + u*8), 16, 0, 0);
    __builtin_amdgcn_global_load_lds(
      (const __attribute__((address_space(1))) void*)(usrc + (size_t)u*8),
      (__attribute__((address_space(3))) void*)(Ul + u*8), 16, 0, 0);
  }
  __syncthreads();   // staging drained

  unsigned short* hgbase = hgrp + (size_t)g*65536;   // [par2][hb32][row64][c16] u16

  if (w >= 4){
    // ================= x-GEMM producer wave =================
    const int w2 = w - 4;          // 0..1, rows w2*32..+32 of the group's 64
    float biasv[4];
    #pragma unroll
    for (int gf = 0; gf < 4; ++gf)
      biasv[gf] = bias_pk[((d*32 + hb)*4 + gf)*16 + jl];

    for (int s = 0; s < TT; ++s){
      const int t = d ? (TT-1-s) : s;
      if (s >= 2){
        while (__hip_atomic_load(&cseq[2*w2],   __ATOMIC_ACQUIRE, __HIP_MEMORY_SCOPE_WORKGROUP) < s-1 ||
               __hip_atomic_load(&cseq[2*w2+1], __ATOMIC_ACQUIRE, __HIP_MEMORY_SCOPE_WORKGROUP) < s-1)
          __builtin_amdgcn_s_sleep(1);
      }
      const unsigned short* xb = xtr + ((size_t)t*BB + m0 + w2*32)*DD;
      bf16x8 xa[2][16];
      #pragma unroll
      for (int ks = 0; ks < 16; ++ks)
        #pragma unroll
        for (int am = 0; am < 2; ++am)
          xa[am][ks] = *(const bf16x8*)(xb + (size_t)(am*16 + jl)*DD + ks*32 + q*8);

      f32x4 acc[2][4];
      #pragma unroll
      for (int am = 0; am < 2; ++am)
        #pragma unroll
        for (int gf = 0; gf < 4; ++gf){
          float bv = biasv[gf];
          acc[am][gf] = (f32x4){bv, bv, bv, bv};
        }

      #pragma unroll
      for (int ks = 0; ks < 16; ++ks){
        #pragma unroll
        for (int gf = 0; gf < 4; ++gf){
          bf16x8 b = *(const bf16x8*)(Wl + ((ks*4 + gf)*64 + lane)*8);
          #pragma unroll
          for (int am = 0; am < 2; ++am)
            acc[am][gf] = __builtin_amdgcn_mfma_f32_16x16x32_bf16(xa[am][ks], b, acc[am][gf], 0, 0, 0);
        }
      }

      const int slot = s & 1;
      #pragma unroll
      for (int am = 0; am < 2; ++am)
        #pragma unroll
        for (int gf = 0; gf < 4; ++gf)
          #pragma unroll
          for (int rr = 0; rr < 4; ++rr)
            ringB[slot][(w2*32 + am*16 + q*4 + rr)*64 + ((gf*16 + jl) ^ (q << 2))] =
                f2bf(acc[am][gf][rr]);
      __hip_atomic_store(&xseq[w2], s+1, __ATOMIC_RELEASE, __HIP_MEMORY_SCOPE_WORKGROUP);
    }
  } else {
    // ================= chain wave (rows w*16..+16 of group) =================
    float cst[4] = {0.f, 0.f, 0.f, 0.f};
    int* myflags = flags + g*128;   // 128 words per group: [hb32][w4]

    for (int s = 0; s < TT; ++s){
      const int t   = d ? (TT-1-s) : s;
      const int par = s & 1;

      // ---- zx from LDS ring (swizzled cols, same mapping as producer) ----
      while (__hip_atomic_load(&xseq[w >> 1], __ATOMIC_ACQUIRE, __HIP_MEMORY_SCOPE_WORKGROUP) < s+1)
        __builtin_amdgcn_s_sleep(1);
      float zx[4][4];
      #pragma unroll
      for (int gf = 0; gf < 4; ++gf)
        #pragma unroll
        for (int rr = 0; rr < 4; ++rr)
          zx[gf][rr] = bf2f(ringB[par][(w*16 + q*4 + rr)*64 + ((gf*16 + jl) ^ (q << 2))]);
      __hip_atomic_store(&cseq[w], s+1, __ATOMIC_RELEASE, __HIP_MEMORY_SCOPE_WORKGROUP);

      // ---- chain wait: poll all 128 per-wave flags directly (2/lane) ----
      if (s > 0){
        for (;;){
          int v0 = __hip_atomic_load(myflags + lane,      __ATOMIC_RELAXED, __HIP_MEMORY_SCOPE_AGENT);
          int v1 = __hip_atomic_load(myflags + 64 + lane, __ATOMIC_RELAXED, __HIP_MEMORY_SCOPE_AGENT);
          if (__all(v0 >= s && v1 >= s)) break;
          __builtin_amdgcn_s_sleep(1);
        }
      }
      asm volatile("" ::: "memory");

      // ---- h A-fragments (16 rows x 512 cols = 16KB) ----
      const char* hgp = (const char*)hgbase + (size_t)par*65536;
      union Q { i32x4 i; unsigned long long u[2]; bf16x8 v; } ha[16];
      if (pure){
        #pragma unroll
        for (int ks = 0; ks < 16; ++ks){
          const void* p = (const void*)
              (hgp + (((ks*2 + (q>>1))*64 + w*16 + jl)*32 + (q&1)*16));
          asm volatile("global_load_dwordx4 %0, %1, off sc0"
                       : "=v"(ha[ks].i) : "v"(p));
        }
        asm volatile("s_waitcnt vmcnt(0)" ::: "memory");
        __builtin_amdgcn_sched_barrier(0);
      } else {
        #pragma unroll
        for (int ks = 0; ks < 16; ++ks){
          const unsigned long long* p = (const unsigned long long*)
              (hgp + (((ks*2 + (q>>1))*64 + w*16 + jl)*32 + (q&1)*16));
          ha[ks].u[0] = __hip_atomic_load(p,     __ATOMIC_RELAXED, __HIP_MEMORY_SCOPE_AGENT);
          ha[ks].u[1] = __hip_atomic_load(p + 1, __ATOMIC_RELAXED, __HIP_MEMORY_SCOPE_AGENT);
        }
      }

      f32x4 acc[4];
      #pragma unroll
      for (int gf = 0; gf < 4; ++gf) acc[gf] = (f32x4){0.f,0.f,0.f,0.f};

      #pragma unroll
      for (int ks = 0; ks < 16; ++ks){
        #pragma unroll
        for (int gf = 0; gf < 4; ++gf){
          bf16x8 b = *(const bf16x8*)(Ul + ((ks*4 + gf)*64 + lane)*8);
          acc[gf] = __builtin_amdgcn_mfma_f32_16x16x32_bf16(ha[ks].v, b, acc[gf], 0, 0, 0);
        }
      }

      // ---- epilogue: gates, c in regs; h stores, drain, own-wave flag ----
      unsigned short* hc = hgbase + (size_t)(((s+1)&1)*32 + hb)*1024;  // [row64][c16]
      float hov[4];
      #pragma unroll
      for (int rr = 0; rr < 4; ++rr){
        float zi = acc[0][rr] + zx[0][rr];
        float zf = acc[1][rr] + zx[1][rr];
        float zg = acc[2][rr] + zx[2][rr];
        float zo = acc[3][rr] + zx[3][rr];
        float i_ = sigf(zi);
        float f_ = sigf(zf);
        float g_ = tanhfast(zg);
        float o_ = sigf(zo);
        float c  = f_*cst[rr] + i_*g_;
        cst[rr] = c;
        float h = o_*tanhfast(c);
        hov[rr] = h;

        int row64 = w*16 + q*4 + rr;
        unsigned short h16 = f2bf(h);
        int other = __shfl_xor((int)h16, 1);
        if (!(jl & 1)){
          unsigned int pack = (unsigned int)h16 | (((unsigned int)other & 0xFFFFu) << 16);
          unsigned int* dst = (unsigned int*)(hc + row64*16 + (jl & ~1));
          if (pure) *dst = pack;
          else __hip_atomic_store(dst, pack, __ATOMIC_RELAXED, __HIP_MEMORY_SCOPE_AGENT);
        }
      }

      asm volatile("s_waitcnt vmcnt(0)" ::: "memory");  // h stores committed
      if (lane == 0)
        __hip_atomic_store(myflags + hb*4 + w, s + 1, __ATOMIC_RELAXED, __HIP_MEMORY_SCOPE_AGENT);

      // out stores AFTER the signal (off the critical chain)
      #pragma unroll
      for (int rr = 0; rr < 4; ++rr){
        int b_ = m0 + w*16 + q*4 + rr;
        out[((size_t)b_*TT + t)*(2*HH) + (size_t)d*HH + hb*16 + jl] = hov[rr];
      }
    }
  }
}

// sent_emb[b][n] = word_emb[b][T-1][n] (n<H) or word_emb[b][0][n] (n>=H)
__global__ void final_k(float* __restrict__ out){
  int i = blockIdx.x*blockDim.x + threadIdx.x;
  if (i < BB*2*HH){
    int b = i >> 10;
    int n = i & 1023;
    int t = (n < HH) ? (TT-1) : 0;
    out[(size_t)BB*TT*2*HH + i] = out[((size_t)b*TT + t)*2*HH + n];
  }
}

extern "C" void kernel_launch(void* const* d_in, const int* in_sizes, int n_in,
                              void* d_out, int out_size, void* d_ws, size_t ws_size,
                              hipStream_t stream)
{
  const float* x   = (const float*)d_in[0];
  const float* Wf  = (const float*)d_in[1];
  const float* Uf  = (const float*)d_in[2];
  const float* bf_ = (const float*)d_in[3];
  const float* Wb  = (const float*)d_in[4];
  const float* Ub  = (const float*)d_in[5];
  const float* bb_ = (const float*)d_in[6];
  float* out = (float*)d_out;

  char* ws = (char*)d_ws;
  unsigned short* xtr  = (unsigned short*)(ws);              // 33,554,432 B
  unsigned short* wupk = (unsigned short*)(ws + 33554432);   //  8,388,608 B
  float* bias_pk       = (float*)(ws + 41943040);            //     16,384 B
  unsigned short* hgrp = (unsigned short*)(ws + 41959424);   //  2,097,152 B [g8][par2][hb32][row64][c16]
  int* flags           = (int*)(ws + 44056576);              //      4,096 B [g8][hb32][w4]
  int* xcdcnt          = (int*)(ws + 44060672);              //         64 B

  hipMemsetAsync(hgrp, 0, 2097152, stream);
  hipMemsetAsync(flags, 0, 4096, stream);
  hipMemsetAsync(xcdcnt, 0, 64, stream);

  prep_x_k   <<<2048, 256, 0, stream>>>(x, xtr);
  prep_wu_k  <<<4096, 256, 0, stream>>>(Wf, Uf, Wb, Ub, wupk);
  prep_bias_k<<<16,   256, 0, stream>>>(bf_, bb_, bias_pk);

  lstm_fused_k<<<256, 384, 0, stream>>>(xtr, wupk, bias_pk, hgrp, flags, xcdcnt, out);

  final_k<<<1024, 256, 0, stream>>>(out);
}

// Round 15
// 571.032 us; speedup vs baseline: 1.5266x; 1.5266x over previous
//
#include <hip/hip_runtime.h>
#include <stdint.h>

#define BB 256
#define TT 128
#define DD 512
#define HH 512
#define G4 2048      // 4H

typedef short bf16x8 __attribute__((ext_vector_type(8)));
typedef float f32x4  __attribute__((ext_vector_type(4)));
typedef int   i32x4  __attribute__((ext_vector_type(4)));

__device__ __forceinline__ unsigned short f2bf(float f){
  union { float f; unsigned u; } v; v.f = f;
  unsigned u = v.u;
  unsigned r = (u + 0x7FFFu + ((u >> 16) & 1u)) >> 16;
  return (unsigned short)r;
}
__device__ __forceinline__ float bf2f(unsigned short s){
  union { unsigned u; float f; } v; v.u = ((unsigned)s) << 16;
  return v.f;
}
__device__ __forceinline__ float sigf(float x){
  return __builtin_amdgcn_rcpf(1.0f + __expf(-x));
}
__device__ __forceinline__ float tanhfast(float x){
  return 1.0f - 2.0f*__builtin_amdgcn_rcpf(1.0f + __expf(2.0f*x));
}

// x [B,T,D] f32 -> xtr [T,B,D] bf16
__global__ void prep_x_k(const float* __restrict__ x, unsigned short* __restrict__ xtr){
  const int n4 = BB*TT*(DD/4);
  for (int i = blockIdx.x*blockDim.x + threadIdx.x; i < n4; i += gridDim.x*blockDim.x){
    int d4 = i & (DD/4 - 1);
    int b  = (i / (DD/4)) & (BB-1);
    int t  = i / ((DD/4)*BB);
    float4 v = *(const float4*)(x + (((size_t)b*TT + t)*DD + (size_t)d4*4));
    ushort4 o;
    o.x = f2bf(v.x); o.y = f2bf(v.y); o.z = f2bf(v.z); o.w = f2bf(v.w);
    *(ushort4*)(xtr + (((size_t)t*BB + b)*DD + (size_t)d4*4)) = o;
  }
}

// wupk[arr][d][hb(32)][ks(16)][gf(4)][lane(64)][e(8)] bf16
__global__ void prep_wu_k(const float* __restrict__ Wf, const float* __restrict__ Uf,
                          const float* __restrict__ Wb, const float* __restrict__ Ub,
                          unsigned short* __restrict__ wupk){
  const int tot = 2*2*32*16*4*64*8;  // 4,194,304
  for (int i = blockIdx.x*blockDim.x + threadIdx.x; i < tot; i += gridDim.x*blockDim.x){
    int e    = i & 7;
    int lane = (i >> 3) & 63;
    int gf   = (i >> 9) & 3;
    int ks   = (i >> 11) & 15;
    int hb   = (i >> 15) & 31;
    int d    = (i >> 20) & 1;
    int arr  = (i >> 21) & 1;
    int jl = lane & 15, q = lane >> 4;
    int n = gf*HH + hb*16 + jl;
    int k = ks*32 + q*8 + e;
    const float* src = arr ? (d ? Ub : Uf) : (d ? Wb : Wf);
    wupk[i] = f2bf(src[(size_t)k*G4 + n]);
  }
}

// bias_pk[d][hb(32)][gf(4)][jl(16)]
__global__ void prep_bias_k(const float* __restrict__ bf_, const float* __restrict__ bb_,
                            float* __restrict__ bias_pk){
  int i = blockIdx.x*blockDim.x + threadIdx.x;
  if (i < 2*32*4*16){
    int jl = i & 15;
    int gf = (i >> 4) & 3;
    int hb = (i >> 6) & 31;
    int d  = i >> 11;
    const float* src = d ? bb_ : bf_;
    bias_pk[i] = src[gf*HH + hb*16 + jl];
  }
}

// Persistent LSTM: R13 structure (wave0 polls 32 flags + LDS go/done fan-out)
// with DUAL-PATH flags: plain fA (XCD-L2, sc0 poll) + agent fB (MALL, R13
// fallback). Consumer uses max(fA,fB) per iteration -> zero-cost fallback.
// 256 blocks x 384 thr (6 waves), 1 block/CU (LDS-forced), regular launch.
// Registration (R10): g = physical XCD, hb = rank; surplus fills deficits.
// Waves 0-3: chain over group-rows w*16..+16. h data: pure -> plain stores +
//   sc0 loads (XCD L2); impure -> agent (R8).
// Waves 4-5: x.W+b producers -> 2-slot swizzled LDS bf16 ring.
__global__ __launch_bounds__(384, 1)
void lstm_fused_k(const unsigned short* __restrict__ xtr,
                  const unsigned short* __restrict__ wupk,
                  const float* __restrict__ bias_pk,
                  unsigned short* hgrp,
                  int* flagA, int* flagB, int* xcdcnt,
                  float* __restrict__ out)
{
  __shared__ __align__(1024) unsigned short Wl[32768];     // 64KB [ks16][gf4][lane][8]
  __shared__ __align__(1024) unsigned short Ul[32768];     // 64KB
  __shared__ __align__(1024) unsigned short ringB[2][4096];// 16KB [slot][row64][col64^swz]
  __shared__ int xseq[2];
  __shared__ int cseq[4];
  __shared__ int go;
  __shared__ int done;
  __shared__ int shId[4];

  const int tid  = threadIdx.x;
  const int lane = tid & 63;
  const int w    = tid >> 6;          // 0..5
  const int jl   = lane & 15, q = lane >> 4;

  // ---- registration (R10-proven): hang-free XCD identity ----
  if (tid == 0){
    unsigned xcd;
    asm volatile("s_getreg_b32 %0, hwreg(HW_REG_XCC_ID)" : "=s"(xcd));
    int x = (int)(xcd & 7);
    int rank = __hip_atomic_fetch_add(&xcdcnt[x], 1, __ATOMIC_RELAXED, __HIP_MEMORY_SCOPE_AGENT);
    __hip_atomic_fetch_add(&xcdcnt[8], 1, __ATOMIC_RELEASE, __HIP_MEMORY_SCOPE_AGENT);
    while (__hip_atomic_load(&xcdcnt[8], __ATOMIC_ACQUIRE, __HIP_MEMORY_SCOPE_AGENT) < 256)
      __builtin_amdgcn_s_sleep(2);
    int n[8];
    #pragma unroll
    for (int i = 0; i < 8; ++i)
      n[i] = __hip_atomic_load(&xcdcnt[i], __ATOMIC_RELAXED, __HIP_MEMORY_SCOPE_AGENT);
    int gg = 0, hh = 0;
    if (rank < 32){ gg = x; hh = rank; }
    else {
      int k = rank - 32;
      for (int i = 0; i < x; ++i) if (n[i] > 32) k += n[i] - 32;
      for (int i = 0; i < 8; ++i){
        int def = 32 - n[i];
        if (def > 0){
          if (k < def){ gg = i; hh = n[i] + k; break; }
          k -= def;
        }
      }
    }
    shId[0] = gg; shId[1] = hh; shId[2] = (n[gg] >= 32) ? 1 : 0;
    go = 0; done = 0;
  }
  if (tid < 2) xseq[tid] = 0;
  if (tid < 4) cseq[tid] = 0;
  __syncthreads();
  const int g    = shId[0];
  const int hb   = shId[1];
  const int pure = shId[2];
  const int d    = g >> 2;
  const int mq   = g & 3;
  const int m0   = mq * 64;

  // ---- stage W and U slices (linear fragment order) ----
  const unsigned short* wsrc = wupk + ((size_t)(0*2 + d)*32 + hb)*32768;
  const unsigned short* usrc = wupk + ((size_t)(1*2 + d)*32 + hb)*32768;
  for (int u = tid; u < 4096; u += 384){
    __builtin_amdgcn_global_load_lds(
      (const __attribute__((address_space(1))) void*)(wsrc + (size_t)u*8),
      (__attribute__((address_space(3))) void*)(Wl + u*8), 16, 0, 0);
    __builtin_amdgcn_global_load_lds(
      (const __attribute__((address_space(1))) void*)(usrc + (size_t)u*8),
      (__attribute__((address_space(3))) void*)(Ul + u*8), 16, 0, 0);
  }
  __syncthreads();   // staging drained

  unsigned short* hgbase = hgrp + (size_t)g*65536;   // [par2][hb32][row64][c16] u16

  if (w >= 4){
    // ================= x-GEMM producer wave =================
    const int w2 = w - 4;          // 0..1, rows w2*32..+32 of the group's 64
    float biasv[4];
    #pragma unroll
    for (int gf = 0; gf < 4; ++gf)
      biasv[gf] = bias_pk[((d*32 + hb)*4 + gf)*16 + jl];

    for (int s = 0; s < TT; ++s){
      const int t = d ? (TT-1-s) : s;
      if (s >= 2){
        while (__hip_atomic_load(&cseq[2*w2],   __ATOMIC_ACQUIRE, __HIP_MEMORY_SCOPE_WORKGROUP) < s-1 ||
               __hip_atomic_load(&cseq[2*w2+1], __ATOMIC_ACQUIRE, __HIP_MEMORY_SCOPE_WORKGROUP) < s-1)
          __builtin_amdgcn_s_sleep(1);
      }
      const unsigned short* xb = xtr + ((size_t)t*BB + m0 + w2*32)*DD;
      bf16x8 xa[2][16];
      #pragma unroll
      for (int ks = 0; ks < 16; ++ks)
        #pragma unroll
        for (int am = 0; am < 2; ++am)
          xa[am][ks] = *(const bf16x8*)(xb + (size_t)(am*16 + jl)*DD + ks*32 + q*8);

      f32x4 acc[2][4];
      #pragma unroll
      for (int am = 0; am < 2; ++am)
        #pragma unroll
        for (int gf = 0; gf < 4; ++gf){
          float bv = biasv[gf];
          acc[am][gf] = (f32x4){bv, bv, bv, bv};
        }

      #pragma unroll
      for (int ks = 0; ks < 16; ++ks){
        #pragma unroll
        for (int gf = 0; gf < 4; ++gf){
          bf16x8 b = *(const bf16x8*)(Wl + ((ks*4 + gf)*64 + lane)*8);
          #pragma unroll
          for (int am = 0; am < 2; ++am)
            acc[am][gf] = __builtin_amdgcn_mfma_f32_16x16x32_bf16(xa[am][ks], b, acc[am][gf], 0, 0, 0);
        }
      }

      const int slot = s & 1;
      #pragma unroll
      for (int am = 0; am < 2; ++am)
        #pragma unroll
        for (int gf = 0; gf < 4; ++gf)
          #pragma unroll
          for (int rr = 0; rr < 4; ++rr)
            ringB[slot][(w2*32 + am*16 + q*4 + rr)*64 + ((gf*16 + jl) ^ (q << 2))] =
                f2bf(acc[am][gf][rr]);
      __hip_atomic_store(&xseq[w2], s+1, __ATOMIC_RELEASE, __HIP_MEMORY_SCOPE_WORKGROUP);
    }
  } else {
    // ================= chain wave (rows w*16..+16 of group) =================
    float cst[4] = {0.f, 0.f, 0.f, 0.f};
    int* fA = flagA + g*64;   // 32 words per group, plain/L2 path
    int* fB = flagB + g*64;   // 32 words per group, agent/MALL path

    for (int s = 0; s < TT; ++s){
      const int t   = d ? (TT-1-s) : s;
      const int par = s & 1;

      // ---- zx from LDS ring (swizzled cols, same mapping as producer) ----
      while (__hip_atomic_load(&xseq[w >> 1], __ATOMIC_ACQUIRE, __HIP_MEMORY_SCOPE_WORKGROUP) < s+1)
        __builtin_amdgcn_s_sleep(1);
      float zx[4][4];
      #pragma unroll
      for (int gf = 0; gf < 4; ++gf)
        #pragma unroll
        for (int rr = 0; rr < 4; ++rr)
          zx[gf][rr] = bf2f(ringB[par][(w*16 + q*4 + rr)*64 + ((gf*16 + jl) ^ (q << 2))]);
      __hip_atomic_store(&cseq[w], s+1, __ATOMIC_RELEASE, __HIP_MEMORY_SCOPE_WORKGROUP);

      // ---- group sync: wave0 polls max(fA, fB), publishes LDS 'go' ----
      if (s > 0){
        if (w == 0){
          for (;;){
            int vA = s, vB = s;
            if (lane < 32){
              vB = __hip_atomic_load(fB + lane, __ATOMIC_RELAXED, __HIP_MEMORY_SCOPE_AGENT);
              if (pure){
                asm volatile("global_load_dword %0, %1, off sc0\n\ts_waitcnt vmcnt(0)"
                             : "=v"(vA) : "v"((const void*)(fA + lane)) : "memory");
              }
            }
            int v = vA > vB ? vA : vB;
            if (__all(v >= s)) break;
            __builtin_amdgcn_s_sleep(1);
          }
          __hip_atomic_store(&go, s, __ATOMIC_RELEASE, __HIP_MEMORY_SCOPE_WORKGROUP);
        } else {
          while (__hip_atomic_load(&go, __ATOMIC_ACQUIRE, __HIP_MEMORY_SCOPE_WORKGROUP) < s)
            __builtin_amdgcn_s_sleep(1);
        }
      }
      asm volatile("" ::: "memory");

      // ---- h A-fragments (16 rows x 512 cols = 16KB) ----
      const char* hgp = (const char*)hgbase + (size_t)par*65536;
      union Q { i32x4 i; unsigned long long u[2]; bf16x8 v; } ha[16];
      if (pure){
        #pragma unroll
        for (int ks = 0; ks < 16; ++ks){
          const void* p = (const void*)
              (hgp + (((ks*2 + (q>>1))*64 + w*16 + jl)*32 + (q&1)*16));
          asm volatile("global_load_dwordx4 %0, %1, off sc0"
                       : "=v"(ha[ks].i) : "v"(p));
        }
        asm volatile("s_waitcnt vmcnt(0)" ::: "memory");
        __builtin_amdgcn_sched_barrier(0);
      } else {
        #pragma unroll
        for (int ks = 0; ks < 16; ++ks){
          const unsigned long long* p = (const unsigned long long*)
              (hgp + (((ks*2 + (q>>1))*64 + w*16 + jl)*32 + (q&1)*16));
          ha[ks].u[0] = __hip_atomic_load(p,     __ATOMIC_RELAXED, __HIP_MEMORY_SCOPE_AGENT);
          ha[ks].u[1] = __hip_atomic_load(p + 1, __ATOMIC_RELAXED, __HIP_MEMORY_SCOPE_AGENT);
        }
      }

      f32x4 acc[4];
      #pragma unroll
      for (int gf = 0; gf < 4; ++gf) acc[gf] = (f32x4){0.f,0.f,0.f,0.f};

      #pragma unroll
      for (int ks = 0; ks < 16; ++ks){
        #pragma unroll
        for (int gf = 0; gf < 4; ++gf){
          bf16x8 b = *(const bf16x8*)(Ul + ((ks*4 + gf)*64 + lane)*8);
          acc[gf] = __builtin_amdgcn_mfma_f32_16x16x32_bf16(ha[ks].v, b, acc[gf], 0, 0, 0);
        }
      }

      // ---- epilogue: gates, c in regs; h stores, drain, done, dual flag ----
      unsigned short* hc = hgbase + (size_t)(((s+1)&1)*32 + hb)*1024;  // [row64][c16]
      float hov[4];
      #pragma unroll
      for (int rr = 0; rr < 4; ++rr){
        float zi = acc[0][rr] + zx[0][rr];
        float zf = acc[1][rr] + zx[1][rr];
        float zg = acc[2][rr] + zx[2][rr];
        float zo = acc[3][rr] + zx[3][rr];
        float i_ = sigf(zi);
        float f_ = sigf(zf);
        float g_ = tanhfast(zg);
        float o_ = sigf(zo);
        float c  = f_*cst[rr] + i_*g_;
        cst[rr] = c;
        float h = o_*tanhfast(c);
        hov[rr] = h;

        int row64 = w*16 + q*4 + rr;
        unsigned short h16 = f2bf(h);
        int other = __shfl_xor((int)h16, 1);
        if (!(jl & 1)){
          unsigned int pack = (unsigned int)h16 | (((unsigned int)other & 0xFFFFu) << 16);
          unsigned int* dst = (unsigned int*)(hc + row64*16 + (jl & ~1));
          if (pure) *dst = pack;
          else __hip_atomic_store(dst, pack, __ATOMIC_RELAXED, __HIP_MEMORY_SCOPE_AGENT);
        }
      }

      asm volatile("s_waitcnt vmcnt(0)" ::: "memory");  // h stores committed
      if (lane == 0)
        __hip_atomic_fetch_add(&done, 1, __ATOMIC_ACQ_REL, __HIP_MEMORY_SCOPE_WORKGROUP);
      if (w == 0){
        while (__hip_atomic_load(&done, __ATOMIC_ACQUIRE, __HIP_MEMORY_SCOPE_WORKGROUP) < 4*(s+1)) {}
        if (lane == 0){
          if (pure){
            int sv = s + 1;
            asm volatile("global_store_dword %0, %1, off"
                         :: "v"((void*)(fA + hb)), "v"(sv) : "memory");
          }
          __hip_atomic_store(fB + hb, s + 1, __ATOMIC_RELAXED, __HIP_MEMORY_SCOPE_AGENT);
        }
      }

      // out stores AFTER the signal (off the critical chain)
      #pragma unroll
      for (int rr = 0; rr < 4; ++rr){
        int b_ = m0 + w*16 + q*4 + rr;
        out[((size_t)b_*TT + t)*(2*HH) + (size_t)d*HH + hb*16 + jl] = hov[rr];
      }
    }
  }
}

// sent_emb[b][n] = word_emb[b][T-1][n] (n<H) or word_emb[b][0][n] (n>=H)
__global__ void final_k(float* __restrict__ out){
  int i = blockIdx.x*blockDim.x + threadIdx.x;
  if (i < BB*2*HH){
    int b = i >> 10;
    int n = i & 1023;
    int t = (n < HH) ? (TT-1) : 0;
    out[(size_t)BB*TT*2*HH + i] = out[((size_t)b*TT + t)*2*HH + n];
  }
}

extern "C" void kernel_launch(void* const* d_in, const int* in_sizes, int n_in,
                              void* d_out, int out_size, void* d_ws, size_t ws_size,
                              hipStream_t stream)
{
  const float* x   = (const float*)d_in[0];
  const float* Wf  = (const float*)d_in[1];
  const float* Uf  = (const float*)d_in[2];
  const float* bf_ = (const float*)d_in[3];
  const float* Wb  = (const float*)d_in[4];
  const float* Ub  = (const float*)d_in[5];
  const float* bb_ = (const float*)d_in[6];
  float* out = (float*)d_out;

  char* ws = (char*)d_ws;
  unsigned short* xtr  = (unsigned short*)(ws);              // 33,554,432 B
  unsigned short* wupk = (unsigned short*)(ws + 33554432);   //  8,388,608 B
  float* bias_pk       = (float*)(ws + 41943040);            //     16,384 B
  unsigned short* hgrp = (unsigned short*)(ws + 41959424);   //  2,097,152 B [g8][par2][hb32][row64][c16]
  int* flagA           = (int*)(ws + 44056576);              //      2,048 B [g8][64]
  int* flagB           = (int*)(ws + 44058624);              //      2,048 B [g8][64]
  int* xcdcnt          = (int*)(ws + 44060672);              //         64 B

  hipMemsetAsync(hgrp, 0, 2097152, stream);
  hipMemsetAsync(flagA, 0, 2048, stream);
  hipMemsetAsync(flagB, 0, 2048, stream);
  hipMemsetAsync(xcdcnt, 0, 64, stream);

  prep_x_k   <<<2048, 256, 0, stream>>>(x, xtr);
  prep_wu_k  <<<4096, 256, 0, stream>>>(Wf, Uf, Wb, Ub, wupk);
  prep_bias_k<<<16,   256, 0, stream>>>(bf_, bb_, bias_pk);

  lstm_fused_k<<<256, 384, 0, stream>>>(xtr, wupk, bias_pk, hgrp, flagA, flagB, xcdcnt, out);

  final_k<<<1024, 256, 0, stream>>>(out);
}